// Round 1
// baseline (349.758 us; speedup 1.0000x reference)
//
#include <hip/hip_runtime.h>
#include <hip/hip_bf16.h>
#include <cstdint>

typedef __bf16 bf16;
typedef bf16 bf16x8 __attribute__((ext_vector_type(8)));
typedef float f32x4 __attribute__((ext_vector_type(4)));

#define MFMA16(a, b, c) __builtin_amdgcn_mfma_f32_16x16x32_bf16(a, b, c, 0, 0, 0)

static constexpr int Bb = 2, Hh = 12, Nn = 2048, Cc = 768, HD = 64;
static constexpr float SCALE = 0.125f;        // HD^-0.5
static constexpr float LOG2E = 1.4426950408889634f;

// ---------------- fp32 -> bf16 conversion (8 elems/thread) ----------------
__global__ __launch_bounds__(256) void cvt_f32_bf16(const float* __restrict__ in,
                                                    bf16* __restrict__ out, int n8) {
    int i = blockIdx.x * blockDim.x + threadIdx.x;
    if (i >= n8) return;
    const float4* p = reinterpret_cast<const float4*>(in) + (size_t)i * 2;
    float4 v0 = p[0], v1 = p[1];
    bf16x8 o;
    o[0] = (bf16)v0.x; o[1] = (bf16)v0.y; o[2] = (bf16)v0.z; o[3] = (bf16)v0.w;
    o[4] = (bf16)v1.x; o[5] = (bf16)v1.y; o[6] = (bf16)v1.z; o[7] = (bf16)v1.w;
    reinterpret_cast<bf16x8*>(out)[i] = o;
}

// ---------------- NT GEMM: y[m][j] = sum_k X[m][k] * W[j][k] ----------------
// MODE 0: store bf16 Q*SCALE to [b][h][n][hd]
// MODE 1: store bf16 K        to [b][h][n][hd]
// MODE 2: store bf16 V        to [b][h][hd][n]   (transposed)
// MODE 3: store f32  y + bias to [m][j] (d_out)
template <int MODE>
__global__ __launch_bounds__(256) void gemm_nt(const bf16* __restrict__ X,
                                               const bf16* __restrict__ W,
                                               const float* __restrict__ bias,
                                               void* __restrict__ Y) {
    constexpr int K = Cc;               // 768
    const int m0 = blockIdx.x * 128;
    const int j0 = blockIdx.y * 64;
    const int w  = threadIdx.x >> 6;
    const int l  = threadIdx.x & 63;
    const int lr = l & 15;              // row (A) / col (B) within fragment
    const int lg = l >> 4;              // k-group
    const int mw = m0 + w * 32;

    f32x4 acc[2][4] = {};
    const bf16* xA = X + (size_t)(mw + lr) * K + lg * 8;
    const bf16* wB = W + (size_t)(j0 + lr) * K + lg * 8;

    for (int k = 0; k < K; k += 32) {
        bf16x8 a[2], b[4];
        a[0] = *reinterpret_cast<const bf16x8*>(xA + k);
        a[1] = *reinterpret_cast<const bf16x8*>(xA + (size_t)16 * K + k);
#pragma unroll
        for (int c = 0; c < 4; c++)
            b[c] = *reinterpret_cast<const bf16x8*>(wB + (size_t)(c * 16) * K + k);
#pragma unroll
        for (int r = 0; r < 2; r++)
#pragma unroll
            for (int c = 0; c < 4; c++)
                acc[r][c] = MFMA16(a[r], b[c], acc[r][c]);
    }

#pragma unroll
    for (int r = 0; r < 2; r++)
#pragma unroll
        for (int c = 0; c < 4; c++)
#pragma unroll
            for (int j = 0; j < 4; j++) {
                const int m   = mw + r * 16 + lg * 4 + j;   // D row = (l>>4)*4 + reg
                const int col = j0 + c * 16 + lr;           // D col = l&15
                const float v = acc[r][c][j];
                if constexpr (MODE == 0 || MODE == 1) {
                    const int bb = m >> 11, n = m & 2047;
                    const int h = col >> 6, hd = col & 63;
                    const float s = (MODE == 0) ? v * SCALE : v;
                    ((bf16*)Y)[(((size_t)(bb * Hh + h)) * Nn + n) * HD + hd] = (bf16)s;
                } else if constexpr (MODE == 2) {
                    const int bb = m >> 11, n = m & 2047;
                    const int h = col >> 6, hd = col & 63;
                    ((bf16*)Y)[(((size_t)(bb * Hh + h)) * HD + hd) * Nn + n] = (bf16)v;
                } else {
                    ((float*)Y)[(size_t)m * Cc + col] = v + bias[col];
                }
            }
}

// ---------------- flash attention ----------------
// grid.x = B*H*(N/64); block = 256 (4 waves), wave handles 16 q-rows
__global__ __launch_bounds__(256) void attn_kernel(const bf16* __restrict__ Q,
                                                   const bf16* __restrict__ Km,
                                                   const bf16* __restrict__ Vt,
                                                   bf16* __restrict__ AO) {
    const int bid = blockIdx.x;
    const int qb  = bid & 31;            // q-block within sequence (N/64 = 32)
    const int bh  = bid >> 5;            // 0..23
    const int w   = threadIdx.x >> 6;
    const int l   = threadIdx.x & 63;
    const int lr  = l & 15;
    const int lg  = l >> 4;
    const int q0  = qb * 64 + w * 16;

    // Q fragments, resident for whole kernel (Q pre-scaled by SCALE)
    const bf16* Qp = Q + ((size_t)bh * Nn + q0 + lr) * HD + lg * 8;
    const bf16x8 qf0 = *reinterpret_cast<const bf16x8*>(Qp);
    const bf16x8 qf1 = *reinterpret_cast<const bf16x8*>(Qp + 32);

    const bf16* Kbase = Km + (size_t)bh * Nn * HD;
    const bf16* Vbase = Vt + (size_t)bh * HD * Nn;

    __shared__ bf16 p_lds[4][16][72];    // row stride 144B = 9 dwords -> conflict-free b128

    f32x4 acc[4] = {};                   // output col-tiles (4 x 16 of HD=64)
    float mrun[4], lrun[4];
#pragma unroll
    for (int j = 0; j < 4; j++) { mrun[j] = -INFINITY; lrun[j] = 0.f; }

    for (int kv = 0; kv < Nn; kv += 64) {
        // ---- scores: S = Q K^T for 16 q-rows x 64 keys ----
        const bf16* Kp = Kbase + ((size_t)kv + lr) * HD + lg * 8;
        f32x4 s[4];
        const f32x4 fz = {0.f, 0.f, 0.f, 0.f};
#pragma unroll
        for (int st = 0; st < 4; st++) {
            bf16x8 k0 = *reinterpret_cast<const bf16x8*>(Kp + (size_t)(st * 16) * HD);
            bf16x8 k1 = *reinterpret_cast<const bf16x8*>(Kp + (size_t)(st * 16) * HD + 32);
            s[st] = MFMA16(qf0, k0, fz);
            s[st] = MFMA16(qf1, k1, s[st]);
        }
        // ---- online softmax (rows live across lanes sharing lg; reduce over lr) ----
        float mt[4];
#pragma unroll
        for (int j = 0; j < 4; j++)
            mt[j] = fmaxf(fmaxf(s[0][j], s[1][j]), fmaxf(s[2][j], s[3][j]));
#pragma unroll
        for (int d = 1; d < 16; d <<= 1)
#pragma unroll
            for (int j = 0; j < 4; j++) mt[j] = fmaxf(mt[j], __shfl_xor(mt[j], d));

        float mnew[4], alpha[4], rs[4];
#pragma unroll
        for (int j = 0; j < 4; j++) {
            mnew[j]  = fmaxf(mrun[j], mt[j]);
            alpha[j] = exp2f((mrun[j] - mnew[j]) * LOG2E);
            mrun[j]  = mnew[j];
            rs[j]    = 0.f;
        }
#pragma unroll
        for (int st = 0; st < 4; st++)
#pragma unroll
            for (int j = 0; j < 4; j++) {
                float p = exp2f((s[st][j] - mnew[j]) * LOG2E);
                rs[j] += p;
                p_lds[w][lg * 4 + j][st * 16 + lr] = (bf16)p;
            }
#pragma unroll
        for (int d = 1; d < 16; d <<= 1)
#pragma unroll
            for (int j = 0; j < 4; j++) rs[j] += __shfl_xor(rs[j], d);
#pragma unroll
        for (int j = 0; j < 4; j++) lrun[j] = lrun[j] * alpha[j] + rs[j];
#pragma unroll
        for (int c = 0; c < 4; c++)
#pragma unroll
            for (int j = 0; j < 4; j++) acc[c][j] *= alpha[j];

        __syncthreads();

        // ---- PV: O += P V ----
        bf16x8 pa0 = *reinterpret_cast<const bf16x8*>(&p_lds[w][lr][lg * 8]);
        bf16x8 pa1 = *reinterpret_cast<const bf16x8*>(&p_lds[w][lr][32 + lg * 8]);
        const bf16* Vp = Vbase + (size_t)lr * Nn + kv + lg * 8;
#pragma unroll
        for (int c = 0; c < 4; c++) {
            bf16x8 v0 = *reinterpret_cast<const bf16x8*>(Vp + (size_t)(c * 16) * Nn);
            bf16x8 v1 = *reinterpret_cast<const bf16x8*>(Vp + (size_t)(c * 16) * Nn + 32);
            acc[c] = MFMA16(pa0, v0, acc[c]);
            acc[c] = MFMA16(pa1, v1, acc[c]);
        }
        __syncthreads();
    }

    // ---- epilogue: normalize, store to [b][n][h*64+hd] bf16 ----
    const int bb = bh / Hh, h = bh % Hh;
#pragma unroll
    for (int c = 0; c < 4; c++)
#pragma unroll
        for (int j = 0; j < 4; j++) {
            const int q = q0 + lg * 4 + j;
            const float v = acc[c][j] / lrun[j];
            AO[((size_t)(bb * Nn + q)) * Cc + h * HD + c * 16 + lr] = (bf16)v;
        }
}

// ---------------- launch ----------------
extern "C" void kernel_launch(void* const* d_in, const int* in_sizes, int n_in,
                              void* d_out, int out_size, void* d_ws, size_t ws_size,
                              hipStream_t stream) {
    const float* x  = (const float*)d_in[0];
    const float* Wq = (const float*)d_in[1];
    const float* Wk = (const float*)d_in[2];
    const float* Wv = (const float*)d_in[3];
    const float* Wo = (const float*)d_in[4];
    const float* bo = (const float*)d_in[5];

    // workspace layout (bytes)
    const size_t XB   = 0;                          // x bf16          6,291,456
    const size_t WQB  = XB + 6291456;               // Wq bf16         1,179,648
    const size_t WKB  = WQB + 1179648;
    const size_t WVB  = WKB + 1179648;
    const size_t WOB  = WVB + 1179648;
    const size_t QB   = WOB + 1179648;              // Q [b][h][n][d]  6,291,456
    const size_t KB   = QB + 6291456;
    const size_t VTB  = KB + 6291456;               // V^T [b][h][d][n]
    const size_t AOB  = VTB + 6291456;              // attn out [m][c]
    const size_t NEED = AOB + 6291456;              // 36,175,872 total
    if (ws_size < NEED) return;                     // fail visibly

    char* ws = (char*)d_ws;
    bf16* xb  = (bf16*)(ws + XB);
    bf16* wqb = (bf16*)(ws + WQB);
    bf16* wkb = (bf16*)(ws + WKB);
    bf16* wvb = (bf16*)(ws + WVB);
    bf16* wob = (bf16*)(ws + WOB);
    bf16* Qb  = (bf16*)(ws + QB);
    bf16* Kb  = (bf16*)(ws + KB);
    bf16* Vtb = (bf16*)(ws + VTB);
    bf16* AOb = (bf16*)(ws + AOB);

    // 1) convert inputs to bf16
    cvt_f32_bf16<<<1536, 256, 0, stream>>>(x, xb, (Bb * Nn * Cc) / 8);
    cvt_f32_bf16<<<288, 256, 0, stream>>>(Wq, wqb, (Cc * Cc) / 8);
    cvt_f32_bf16<<<288, 256, 0, stream>>>(Wk, wkb, (Cc * Cc) / 8);
    cvt_f32_bf16<<<288, 256, 0, stream>>>(Wv, wvb, (Cc * Cc) / 8);
    cvt_f32_bf16<<<288, 256, 0, stream>>>(Wo, wob, (Cc * Cc) / 8);

    // 2) projections
    dim3 gg(32, 12);   // M/128 x N/64
    gemm_nt<0><<<gg, 256, 0, stream>>>(xb, wqb, nullptr, Qb);
    gemm_nt<1><<<gg, 256, 0, stream>>>(xb, wkb, nullptr, Kb);
    gemm_nt<2><<<gg, 256, 0, stream>>>(xb, wvb, nullptr, Vtb);

    // 3) attention
    attn_kernel<<<Bb * Hh * (Nn / 64), 256, 0, stream>>>(Qb, Kb, Vtb, AOb);

    // 4) output projection + bias -> fp32 d_out
    gemm_nt<3><<<gg, 256, 0, stream>>>(AOb, wob, bo, (void*)d_out);
}

// Round 2
// 324.781 us; speedup vs baseline: 1.0769x; 1.0769x over previous
//
#include <hip/hip_runtime.h>
#include <hip/hip_bf16.h>
#include <cstdint>

typedef __bf16 bf16;
typedef bf16 bf16x8 __attribute__((ext_vector_type(8)));
typedef float f32x4 __attribute__((ext_vector_type(4)));
typedef uint32_t u32;

#define MFMA16(a, b, c) __builtin_amdgcn_mfma_f32_16x16x32_bf16(a, b, c, 0, 0, 0)

static constexpr int Bb = 2, Hh = 12, Nn = 2048, Cc = 768, HD = 64;
static constexpr float SCALE = 0.125f;        // HD^-0.5
static constexpr float LOG2E = 1.4426950408889634f;

__device__ inline u32 pkbf(float a, float b) {
    union { struct { uint16_t lo, hi; } s; u32 w; } u;
    u.s.lo = __builtin_bit_cast(uint16_t, (bf16)a);
    u.s.hi = __builtin_bit_cast(uint16_t, (bf16)b);
    return u.w;
}

// ---------------- fp32 -> bf16 conversion (8 elems/thread) ----------------
__global__ __launch_bounds__(256) void cvt_f32_bf16(const float* __restrict__ in,
                                                    bf16* __restrict__ out, int n8) {
    int i = blockIdx.x * blockDim.x + threadIdx.x;
    if (i >= n8) return;
    const float4* p = reinterpret_cast<const float4*>(in) + (size_t)i * 2;
    float4 v0 = p[0], v1 = p[1];
    bf16x8 o;
    o[0] = (bf16)v0.x; o[1] = (bf16)v0.y; o[2] = (bf16)v0.z; o[3] = (bf16)v0.w;
    o[4] = (bf16)v1.x; o[5] = (bf16)v1.y; o[6] = (bf16)v1.z; o[7] = (bf16)v1.w;
    reinterpret_cast<bf16x8*>(out)[i] = o;
}

// 4 weight matrices in one launch (blockIdx.y selects)
__global__ __launch_bounds__(256) void cvt4_f32_bf16(const float* __restrict__ s0, const float* __restrict__ s1,
                                                     const float* __restrict__ s2, const float* __restrict__ s3,
                                                     bf16* __restrict__ d0, bf16* __restrict__ d1,
                                                     bf16* __restrict__ d2, bf16* __restrict__ d3, int n8) {
    int i = blockIdx.x * blockDim.x + threadIdx.x;
    if (i >= n8) return;
    const float* in = blockIdx.y == 0 ? s0 : blockIdx.y == 1 ? s1 : blockIdx.y == 2 ? s2 : s3;
    bf16* out = blockIdx.y == 0 ? d0 : blockIdx.y == 1 ? d1 : blockIdx.y == 2 ? d2 : d3;
    const float4* p = reinterpret_cast<const float4*>(in) + (size_t)i * 2;
    float4 v0 = p[0], v1 = p[1];
    bf16x8 o;
    o[0] = (bf16)v0.x; o[1] = (bf16)v0.y; o[2] = (bf16)v0.z; o[3] = (bf16)v0.w;
    o[4] = (bf16)v1.x; o[5] = (bf16)v1.y; o[6] = (bf16)v1.z; o[7] = (bf16)v1.w;
    reinterpret_cast<bf16x8*>(out)[i] = o;
}

// ---------------- NT GEMM: y[m][j] = sum_k X[m][k] * W[j][k] ----------------
template <int MODE>
__global__ __launch_bounds__(256) void gemm_nt(const bf16* __restrict__ X,
                                               const bf16* __restrict__ W,
                                               const float* __restrict__ bias,
                                               void* __restrict__ Y) {
    constexpr int K = Cc;               // 768
    const int m0 = blockIdx.x * 128;
    const int j0 = blockIdx.y * 64;
    const int w  = threadIdx.x >> 6;
    const int l  = threadIdx.x & 63;
    const int lr = l & 15;
    const int lg = l >> 4;
    const int mw = m0 + w * 32;

    f32x4 acc[2][4] = {};
    const bf16* xA = X + (size_t)(mw + lr) * K + lg * 8;
    const bf16* wB = W + (size_t)(j0 + lr) * K + lg * 8;

    for (int k = 0; k < K; k += 32) {
        bf16x8 a[2], b[4];
        a[0] = *reinterpret_cast<const bf16x8*>(xA + k);
        a[1] = *reinterpret_cast<const bf16x8*>(xA + (size_t)16 * K + k);
#pragma unroll
        for (int c = 0; c < 4; c++)
            b[c] = *reinterpret_cast<const bf16x8*>(wB + (size_t)(c * 16) * K + k);
#pragma unroll
        for (int r = 0; r < 2; r++)
#pragma unroll
            for (int c = 0; c < 4; c++)
                acc[r][c] = MFMA16(a[r], b[c], acc[r][c]);
    }

#pragma unroll
    for (int r = 0; r < 2; r++)
#pragma unroll
        for (int c = 0; c < 4; c++)
#pragma unroll
            for (int j = 0; j < 4; j++) {
                const int m   = mw + r * 16 + lg * 4 + j;
                const int col = j0 + c * 16 + lr;
                const float v = acc[r][c][j];
                if constexpr (MODE == 0 || MODE == 1) {
                    const int bb = m >> 11, n = m & 2047;
                    const int h = col >> 6, hd = col & 63;
                    const float s = (MODE == 0) ? v * SCALE : v;
                    ((bf16*)Y)[(((size_t)(bb * Hh + h)) * Nn + n) * HD + hd] = (bf16)s;
                } else if constexpr (MODE == 2) {
                    const int bb = m >> 11, n = m & 2047;
                    const int h = col >> 6, hd = col & 63;
                    ((bf16*)Y)[(((size_t)(bb * Hh + h)) * HD + hd) * Nn + n] = (bf16)v;
                } else {
                    ((float*)Y)[(size_t)m * Cc + col] = v + bias[col];
                }
            }
}

// ---------------- flash attention v2 ----------------
// 1 wave per block (64 thr). Wave owns 16 q-rows. No barriers.
// Swapped QK: S^T = mfma(K,Q): lane q = l&15, keys = st*16 + lg*4 + j.
// Swapped PV: O^T = mfma(V,P): lane q = l&15, d = c*16 + lg*4 + j.
__global__ __launch_bounds__(64, 3) void attn_kernel(const bf16* __restrict__ Q,
                                                     const bf16* __restrict__ Km,
                                                     const bf16* __restrict__ Vt,
                                                     bf16* __restrict__ AO) {
    const int bid = blockIdx.x;
    const int qb  = bid & 127;           // N/16 = 128 q-blocks
    const int bh  = bid >> 7;            // 0..23
    const int l   = threadIdx.x;
    const int lr  = l & 15;
    const int lg  = l >> 4;
    const int q0  = qb * 16;

    __shared__ u32   p_lds[16 * 36];     // [q][32 words + pad4]  2304 B
    __shared__ float o_lds[64 * 17];     // [d][16 q + pad]       4352 B

    // Q fragments (pre-scaled by SCALE at projection time)
    const bf16* Qp = Q + ((size_t)bh * Nn + q0 + lr) * HD + lg * 8;
    const bf16x8 qf0 = *reinterpret_cast<const bf16x8*>(Qp);
    const bf16x8 qf1 = *reinterpret_cast<const bf16x8*>(Qp + 32);

    const bf16* Kbase = Km + (size_t)bh * Nn * HD;
    const bf16* Vbase = Vt + (size_t)bh * HD * Nn;

    f32x4 acc[4] = {};
    float mrun = -INFINITY, lrun = 0.f;

    bf16x8 ka[8], kb[8], vv[8];

    auto loadK = [&](bf16x8* kr, int t) {
        const bf16* p = Kbase + ((size_t)(t * 64) + lr) * HD + lg * 8;
#pragma unroll
        for (int st = 0; st < 4; st++) {
            kr[st * 2]     = *reinterpret_cast<const bf16x8*>(p + (size_t)(st * 16) * HD);
            kr[st * 2 + 1] = *reinterpret_cast<const bf16x8*>(p + (size_t)(st * 16) * HD + 32);
        }
    };
    auto loadV = [&](int t) {
        const bf16* p = Vbase + (size_t)lr * Nn + t * 64 + lg * 8;
#pragma unroll
        for (int c = 0; c < 4; c++) {
            vv[c * 2]     = *reinterpret_cast<const bf16x8*>(p + (size_t)(c * 16) * Nn);
            vv[c * 2 + 1] = *reinterpret_cast<const bf16x8*>(p + (size_t)(c * 16) * Nn + 32);
        }
    };

    auto TILE = [&](bf16x8* kr) {
        // ---- QK^T (swapped): s[st] covers keys st*16 + lg*4 + j, q = lr ----
        f32x4 s[4];
        const f32x4 fz = {0.f, 0.f, 0.f, 0.f};
        __builtin_amdgcn_s_setprio(1);
#pragma unroll
        for (int st = 0; st < 4; st++) {
            s[st] = MFMA16(kr[st * 2], qf0, fz);
            s[st] = MFMA16(kr[st * 2 + 1], qf1, s[st]);
        }
        __builtin_amdgcn_s_setprio(0);

        // ---- per-lane softmax + 2-shuffle cross-group reduce ----
        float mt = s[0][0];
#pragma unroll
        for (int st = 0; st < 4; st++)
#pragma unroll
            for (int j = 0; j < 4; j++) mt = fmaxf(mt, s[st][j]);
        mt = fmaxf(mt, __shfl_xor(mt, 16));
        mt = fmaxf(mt, __shfl_xor(mt, 32));

        const float mnew  = fmaxf(mrun, mt);
        const float alpha = exp2f((mrun - mnew) * LOG2E);
        const float c1    = mnew * LOG2E;
        float p[4][4];
        float rs = 0.f;
#pragma unroll
        for (int st = 0; st < 4; st++)
#pragma unroll
            for (int j = 0; j < 4; j++) {
                p[st][j] = exp2f(fmaf(s[st][j], LOG2E, -c1));
                rs += p[st][j];
            }
        rs += __shfl_xor(rs, 16);
        rs += __shfl_xor(rs, 32);
        lrun = lrun * alpha + rs;
        mrun = mnew;
#pragma unroll
        for (int c = 0; c < 4; c++) acc[c] *= alpha;

        // ---- pack P -> per-wave LDS (row q=lr, word = k/2) ----
#pragma unroll
        for (int st = 0; st < 4; st++) {
            u32 w0 = pkbf(p[st][0], p[st][1]);
            u32 w1 = pkbf(p[st][2], p[st][3]);
            *reinterpret_cast<uint2*>(&p_lds[lr * 36 + st * 8 + lg * 2]) = make_uint2(w0, w1);
        }
        asm volatile("s_waitcnt lgkmcnt(0)" ::: "memory");
        __builtin_amdgcn_sched_barrier(0);
        const bf16x8 pa0 = *reinterpret_cast<const bf16x8*>(&p_lds[lr * 36 + lg * 4]);
        const bf16x8 pa1 = *reinterpret_cast<const bf16x8*>(&p_lds[lr * 36 + 16 + lg * 4]);

        // ---- PV (swapped): acc = O^T ----
        __builtin_amdgcn_s_setprio(1);
#pragma unroll
        for (int c = 0; c < 4; c++) {
            acc[c] = MFMA16(vv[c * 2], pa0, acc[c]);
            acc[c] = MFMA16(vv[c * 2 + 1], pa1, acc[c]);
        }
        __builtin_amdgcn_s_setprio(0);
    };

    loadK(ka, 0);
#pragma unroll 1
    for (int t = 0; t < 32; t += 2) {
        loadV(t);
        loadK(kb, t + 1);
        TILE(ka);
        loadV(t + 1);
        if (t + 2 < 32) loadK(ka, t + 2);
        TILE(kb);
    }

    // ---- epilogue: O^T -> LDS -> coalesced bf16 store ----
    const float rinv = 1.0f / lrun;
#pragma unroll
    for (int c = 0; c < 4; c++)
#pragma unroll
        for (int j = 0; j < 4; j++)
            o_lds[(c * 16 + lg * 4 + j) * 17 + lr] = acc[c][j] * rinv;
    asm volatile("s_waitcnt lgkmcnt(0)" ::: "memory");
    __builtin_amdgcn_sched_barrier(0);

    const int bb = bh / Hh, h = bh % Hh;
    const int qq = l >> 2, dc = (l & 3) * 16;
    bf16x8 o0, o1;
#pragma unroll
    for (int dd = 0; dd < 8; dd++) o0[dd] = (bf16)o_lds[(dc + dd) * 17 + qq];
#pragma unroll
    for (int dd = 0; dd < 8; dd++) o1[dd] = (bf16)o_lds[(dc + 8 + dd) * 17 + qq];
    bf16* dst = AO + ((size_t)(bb * Nn) + q0 + qq) * Cc + h * 64 + dc;
    *reinterpret_cast<bf16x8*>(dst) = o0;
    *reinterpret_cast<bf16x8*>(dst + 8) = o1;
}

// ---------------- launch ----------------
extern "C" void kernel_launch(void* const* d_in, const int* in_sizes, int n_in,
                              void* d_out, int out_size, void* d_ws, size_t ws_size,
                              hipStream_t stream) {
    const float* x  = (const float*)d_in[0];
    const float* Wq = (const float*)d_in[1];
    const float* Wk = (const float*)d_in[2];
    const float* Wv = (const float*)d_in[3];
    const float* Wo = (const float*)d_in[4];
    const float* bo = (const float*)d_in[5];

    const size_t XB   = 0;
    const size_t WQB  = XB + 6291456;
    const size_t WKB  = WQB + 1179648;
    const size_t WVB  = WKB + 1179648;
    const size_t WOB  = WVB + 1179648;
    const size_t QB   = WOB + 1179648;
    const size_t KB   = QB + 6291456;
    const size_t VTB  = KB + 6291456;
    const size_t AOB  = VTB + 6291456;
    const size_t NEED = AOB + 6291456;
    if (ws_size < NEED) return;

    char* ws = (char*)d_ws;
    bf16* xb  = (bf16*)(ws + XB);
    bf16* wqb = (bf16*)(ws + WQB);
    bf16* wkb = (bf16*)(ws + WKB);
    bf16* wvb = (bf16*)(ws + WVB);
    bf16* wob = (bf16*)(ws + WOB);
    bf16* Qb  = (bf16*)(ws + QB);
    bf16* Kb  = (bf16*)(ws + KB);
    bf16* Vtb = (bf16*)(ws + VTB);
    bf16* AOb = (bf16*)(ws + AOB);

    cvt_f32_bf16<<<1536, 256, 0, stream>>>(x, xb, (Bb * Nn * Cc) / 8);
    cvt4_f32_bf16<<<dim3(288, 4), 256, 0, stream>>>(Wq, Wk, Wv, Wo, wqb, wkb, wvb, wob, (Cc * Cc) / 8);

    dim3 gg(32, 12);
    gemm_nt<0><<<gg, 256, 0, stream>>>(xb, wqb, nullptr, Qb);
    gemm_nt<1><<<gg, 256, 0, stream>>>(xb, wkb, nullptr, Kb);
    gemm_nt<2><<<gg, 256, 0, stream>>>(xb, wvb, nullptr, Vtb);

    attn_kernel<<<Bb * Hh * (Nn / 16), 64, 0, stream>>>(Qb, Kb, Vtb, AOb);

    gemm_nt<3><<<gg, 256, 0, stream>>>(AOb, wob, bo, (void*)d_out);
}

// Round 3
// 314.965 us; speedup vs baseline: 1.1105x; 1.0312x over previous
//
#include <hip/hip_runtime.h>
#include <hip/hip_bf16.h>
#include <cstdint>

typedef __bf16 bf16;
typedef bf16 bf16x8 __attribute__((ext_vector_type(8)));
typedef float f32x4 __attribute__((ext_vector_type(4)));
typedef uint32_t u32;

#define MFMA16(a, b, c) __builtin_amdgcn_mfma_f32_16x16x32_bf16(a, b, c, 0, 0, 0)

static constexpr int Bb = 2, Hh = 12, Nn = 2048, Cc = 768, HD = 64;
static constexpr float SCALE = 0.125f;        // HD^-0.5
static constexpr float LOG2E = 1.4426950408889634f;

__device__ inline u32 pkbf(float a, float b) {
    union { struct { uint16_t lo, hi; } s; u32 w; } u;
    u.s.lo = __builtin_bit_cast(uint16_t, (bf16)a);
    u.s.hi = __builtin_bit_cast(uint16_t, (bf16)b);
    return u.w;
}

// ---------------- fp32 -> bf16 conversion (8 elems/thread) ----------------
__global__ __launch_bounds__(256) void cvt_f32_bf16(const float* __restrict__ in,
                                                    bf16* __restrict__ out, int n8) {
    int i = blockIdx.x * blockDim.x + threadIdx.x;
    if (i >= n8) return;
    const float4* p = reinterpret_cast<const float4*>(in) + (size_t)i * 2;
    float4 v0 = p[0], v1 = p[1];
    bf16x8 o;
    o[0] = (bf16)v0.x; o[1] = (bf16)v0.y; o[2] = (bf16)v0.z; o[3] = (bf16)v0.w;
    o[4] = (bf16)v1.x; o[5] = (bf16)v1.y; o[6] = (bf16)v1.z; o[7] = (bf16)v1.w;
    reinterpret_cast<bf16x8*>(out)[i] = o;
}

__global__ __launch_bounds__(256) void cvt4_f32_bf16(const float* __restrict__ s0, const float* __restrict__ s1,
                                                     const float* __restrict__ s2, const float* __restrict__ s3,
                                                     bf16* __restrict__ d0, bf16* __restrict__ d1,
                                                     bf16* __restrict__ d2, bf16* __restrict__ d3, int n8) {
    int i = blockIdx.x * blockDim.x + threadIdx.x;
    if (i >= n8) return;
    const float* in = blockIdx.y == 0 ? s0 : blockIdx.y == 1 ? s1 : blockIdx.y == 2 ? s2 : s3;
    bf16* out = blockIdx.y == 0 ? d0 : blockIdx.y == 1 ? d1 : blockIdx.y == 2 ? d2 : d3;
    const float4* p = reinterpret_cast<const float4*>(in) + (size_t)i * 2;
    float4 v0 = p[0], v1 = p[1];
    bf16x8 o;
    o[0] = (bf16)v0.x; o[1] = (bf16)v0.y; o[2] = (bf16)v0.z; o[3] = (bf16)v0.w;
    o[4] = (bf16)v1.x; o[5] = (bf16)v1.y; o[6] = (bf16)v1.z; o[7] = (bf16)v1.w;
    reinterpret_cast<bf16x8*>(out)[i] = o;
}

// ---------------- fused QKV GEMM: W = [Wq;Wk;Wv] (2304 x 768) ----------------
// blockIdx.y in [0,36): group = y/12 (0=Q,1=K,2=V), col-within-768 = (y%12)*64
__global__ __launch_bounds__(256) void gemm_qkv(const bf16* __restrict__ X,
                                                const bf16* __restrict__ W,
                                                bf16* __restrict__ Qb,
                                                bf16* __restrict__ Kb,
                                                bf16* __restrict__ Vtb) {
    constexpr int K = Cc;
    const int m0  = blockIdx.x * 128;
    const int grp = blockIdx.y / 12;
    const int j0  = (blockIdx.y % 12) * 64;      // col within the 768-wide group
    const int w   = threadIdx.x >> 6;
    const int l   = threadIdx.x & 63;
    const int lr  = l & 15;
    const int lg  = l >> 4;
    const int mw  = m0 + w * 32;

    f32x4 acc[2][4] = {};
    const bf16* xA = X + (size_t)(mw + lr) * K + lg * 8;
    const bf16* wB = W + (size_t)(blockIdx.y * 64 + lr) * K + lg * 8;

    for (int k = 0; k < K; k += 32) {
        bf16x8 a[2], b[4];
        a[0] = *reinterpret_cast<const bf16x8*>(xA + k);
        a[1] = *reinterpret_cast<const bf16x8*>(xA + (size_t)16 * K + k);
#pragma unroll
        for (int c = 0; c < 4; c++)
            b[c] = *reinterpret_cast<const bf16x8*>(wB + (size_t)(c * 16) * K + k);
#pragma unroll
        for (int r = 0; r < 2; r++)
#pragma unroll
            for (int c = 0; c < 4; c++)
                acc[r][c] = MFMA16(a[r], b[c], acc[r][c]);
    }

#pragma unroll
    for (int r = 0; r < 2; r++)
#pragma unroll
        for (int c = 0; c < 4; c++)
#pragma unroll
            for (int j = 0; j < 4; j++) {
                const int m   = mw + r * 16 + lg * 4 + j;
                const int col = j0 + c * 16 + lr;
                const int bb = m >> 11, n = m & 2047;
                const int h = col >> 6, hd = col & 63;
                const float v = acc[r][c][j];
                if (grp == 0) {
                    Qb[(((size_t)(bb * Hh + h)) * Nn + n) * HD + hd] = (bf16)(v * SCALE);
                } else if (grp == 1) {
                    Kb[(((size_t)(bb * Hh + h)) * Nn + n) * HD + hd] = (bf16)v;
                } else {
                    Vtb[(((size_t)(bb * Hh + h)) * HD + hd) * Nn + n] = (bf16)v;
                }
            }
}

// ---------------- output projection: BM=64 tiles for occupancy ----------------
__global__ __launch_bounds__(256) void gemm_proj(const bf16* __restrict__ X,
                                                 const bf16* __restrict__ W,
                                                 const float* __restrict__ bias,
                                                 float* __restrict__ Y) {
    constexpr int K = Cc;
    const int m0 = blockIdx.x * 64;
    const int j0 = blockIdx.y * 64;
    const int w  = threadIdx.x >> 6;
    const int l  = threadIdx.x & 63;
    const int lr = l & 15;
    const int lg = l >> 4;
    const int mw = m0 + w * 16;

    f32x4 acc[4] = {};
    const bf16* xA = X + (size_t)(mw + lr) * K + lg * 8;
    const bf16* wB = W + (size_t)(j0 + lr) * K + lg * 8;

    for (int k = 0; k < K; k += 32) {
        bf16x8 a = *reinterpret_cast<const bf16x8*>(xA + k);
        bf16x8 b[4];
#pragma unroll
        for (int c = 0; c < 4; c++)
            b[c] = *reinterpret_cast<const bf16x8*>(wB + (size_t)(c * 16) * K + k);
#pragma unroll
        for (int c = 0; c < 4; c++)
            acc[c] = MFMA16(a, b[c], acc[c]);
    }

#pragma unroll
    for (int c = 0; c < 4; c++)
#pragma unroll
        for (int j = 0; j < 4; j++) {
            const int m   = mw + lg * 4 + j;
            const int col = j0 + c * 16 + lr;
            Y[(size_t)m * Cc + col] = acc[c][j] + bias[col];
        }
}

// ---------------- flash attention v3: pinned prefetch pipeline ----------------
// 1 wave/block, 16 q-rows/wave, no barriers. K double-buffered in regs
// (1 tile ahead), V single-buffered (issued at tile start, used at tile end).
// sched_barrier(0) after each prefetch block pins loads against sinking.
__global__ __launch_bounds__(64, 3) void attn_kernel(const bf16* __restrict__ Q,
                                                     const bf16* __restrict__ Km,
                                                     const bf16* __restrict__ Vt,
                                                     bf16* __restrict__ AO) {
    const int bid = blockIdx.x;
    const int qb  = bid & 127;
    const int bh  = bid >> 7;
    const int l   = threadIdx.x;
    const int lr  = l & 15;
    const int lg  = l >> 4;
    const int q0  = qb * 16;

    __shared__ u32   p_lds[16 * 36];
    __shared__ float o_lds[64 * 17];

    const bf16* Qp = Q + ((size_t)bh * Nn + q0 + lr) * HD + lg * 8;
    const bf16x8 qf0 = *reinterpret_cast<const bf16x8*>(Qp);
    const bf16x8 qf1 = *reinterpret_cast<const bf16x8*>(Qp + 32);

    const bf16* Kbase = Km + (size_t)bh * Nn * HD;
    const bf16* Vbase = Vt + (size_t)bh * HD * Nn;

    f32x4 acc[4] = {};
    float mrun = -INFINITY, lrun = 0.f;

    bf16x8 ka[8], kb[8], vv[8];

    auto loadK = [&](bf16x8* kr, int t) {
        const bf16* p = Kbase + ((size_t)(t * 64) + lr) * HD + lg * 8;
#pragma unroll
        for (int st = 0; st < 4; st++) {
            kr[st * 2]     = *reinterpret_cast<const bf16x8*>(p + (size_t)(st * 16) * HD);
            kr[st * 2 + 1] = *reinterpret_cast<const bf16x8*>(p + (size_t)(st * 16) * HD + 32);
        }
    };
    auto loadV = [&](int t) {
        const bf16* p = Vbase + (size_t)lr * Nn + t * 64 + lg * 8;
#pragma unroll
        for (int c = 0; c < 4; c++) {
            vv[c * 2]     = *reinterpret_cast<const bf16x8*>(p + (size_t)(c * 16) * Nn);
            vv[c * 2 + 1] = *reinterpret_cast<const bf16x8*>(p + (size_t)(c * 16) * Nn + 32);
        }
    };

    auto TILE = [&](bf16x8* kr) {
        f32x4 s[4];
        const f32x4 fz = {0.f, 0.f, 0.f, 0.f};
        __builtin_amdgcn_s_setprio(1);
#pragma unroll
        for (int st = 0; st < 4; st++) {
            s[st] = MFMA16(kr[st * 2], qf0, fz);
            s[st] = MFMA16(kr[st * 2 + 1], qf1, s[st]);
        }
        __builtin_amdgcn_s_setprio(0);

        float mt = s[0][0];
#pragma unroll
        for (int st = 0; st < 4; st++)
#pragma unroll
            for (int j = 0; j < 4; j++) mt = fmaxf(mt, s[st][j]);
        mt = fmaxf(mt, __shfl_xor(mt, 16));
        mt = fmaxf(mt, __shfl_xor(mt, 32));

        const float mnew  = fmaxf(mrun, mt);
        const float alpha = exp2f((mrun - mnew) * LOG2E);
        const float c1    = mnew * LOG2E;
        float p[4][4];
        float rs = 0.f;
#pragma unroll
        for (int st = 0; st < 4; st++)
#pragma unroll
            for (int j = 0; j < 4; j++) {
                p[st][j] = exp2f(fmaf(s[st][j], LOG2E, -c1));
                rs += p[st][j];
            }
        rs += __shfl_xor(rs, 16);
        rs += __shfl_xor(rs, 32);
        lrun = lrun * alpha + rs;
        mrun = mnew;
#pragma unroll
        for (int c = 0; c < 4; c++) acc[c] *= alpha;

#pragma unroll
        for (int st = 0; st < 4; st++) {
            u32 w0 = pkbf(p[st][0], p[st][1]);
            u32 w1 = pkbf(p[st][2], p[st][3]);
            *reinterpret_cast<uint2*>(&p_lds[lr * 36 + st * 8 + lg * 2]) = make_uint2(w0, w1);
        }
        asm volatile("s_waitcnt lgkmcnt(0)" ::: "memory");
        __builtin_amdgcn_sched_barrier(0);
        const bf16x8 pa0 = *reinterpret_cast<const bf16x8*>(&p_lds[lr * 36 + lg * 4]);
        const bf16x8 pa1 = *reinterpret_cast<const bf16x8*>(&p_lds[lr * 36 + 16 + lg * 4]);

        __builtin_amdgcn_s_setprio(1);
#pragma unroll
        for (int c = 0; c < 4; c++) {
            acc[c] = MFMA16(vv[c * 2], pa0, acc[c]);
            acc[c] = MFMA16(vv[c * 2 + 1], pa1, acc[c]);
        }
        __builtin_amdgcn_s_setprio(0);
    };

    loadK(ka, 0);
#pragma unroll 1
    for (int t = 0; t < 32; t += 2) {
        loadV(t);                                // V for TILE(ka), used after softmax
        loadK(kb, t + 1);                        // K one tile ahead
        __builtin_amdgcn_sched_barrier(0);       // pin: loads may not sink into TILE
        TILE(ka);
        loadV(t + 1);
        if (t + 2 < 32) loadK(ka, t + 2);
        __builtin_amdgcn_sched_barrier(0);
        TILE(kb);
    }

    const float rinv = 1.0f / lrun;
#pragma unroll
    for (int c = 0; c < 4; c++)
#pragma unroll
        for (int j = 0; j < 4; j++)
            o_lds[(c * 16 + lg * 4 + j) * 17 + lr] = acc[c][j] * rinv;
    asm volatile("s_waitcnt lgkmcnt(0)" ::: "memory");
    __builtin_amdgcn_sched_barrier(0);

    const int bb = bh / Hh, h = bh % Hh;
    const int qq = l >> 2, dc = (l & 3) * 16;
    bf16x8 o0, o1;
#pragma unroll
    for (int dd = 0; dd < 8; dd++) o0[dd] = (bf16)o_lds[(dc + dd) * 17 + qq];
#pragma unroll
    for (int dd = 0; dd < 8; dd++) o1[dd] = (bf16)o_lds[(dc + 8 + dd) * 17 + qq];
    bf16* dst = AO + ((size_t)(bb * Nn) + q0 + qq) * Cc + h * 64 + dc;
    *reinterpret_cast<bf16x8*>(dst) = o0;
    *reinterpret_cast<bf16x8*>(dst + 8) = o1;
}

// ---------------- launch ----------------
extern "C" void kernel_launch(void* const* d_in, const int* in_sizes, int n_in,
                              void* d_out, int out_size, void* d_ws, size_t ws_size,
                              hipStream_t stream) {
    const float* x  = (const float*)d_in[0];
    const float* Wq = (const float*)d_in[1];
    const float* Wk = (const float*)d_in[2];
    const float* Wv = (const float*)d_in[3];
    const float* Wo = (const float*)d_in[4];
    const float* bo = (const float*)d_in[5];

    const size_t XB    = 0;                       // x bf16        6,291,456
    const size_t WQKVB = XB + 6291456;            // [Wq;Wk;Wv]    3,538,944
    const size_t WOB   = WQKVB + 3538944;         // Wo bf16       1,179,648
    const size_t QB    = WOB + 1179648;
    const size_t KB    = QB + 6291456;
    const size_t VTB   = KB + 6291456;
    const size_t AOB   = VTB + 6291456;
    const size_t NEED  = AOB + 6291456;           // 36,175,872
    if (ws_size < NEED) return;

    char* ws = (char*)d_ws;
    bf16* xb   = (bf16*)(ws + XB);
    bf16* wqkv = (bf16*)(ws + WQKVB);
    bf16* wob  = (bf16*)(ws + WOB);
    bf16* Qb   = (bf16*)(ws + QB);
    bf16* Kb   = (bf16*)(ws + KB);
    bf16* Vtb  = (bf16*)(ws + VTB);
    bf16* AOb  = (bf16*)(ws + AOB);

    cvt_f32_bf16<<<1536, 256, 0, stream>>>(x, xb, (Bb * Nn * Cc) / 8);
    cvt4_f32_bf16<<<dim3(288, 4), 256, 0, stream>>>(Wq, Wk, Wv, Wo,
                                                    wqkv, wqkv + 589824, wqkv + 1179648, wob,
                                                    (Cc * Cc) / 8);

    gemm_qkv<<<dim3(32, 36), 256, 0, stream>>>(xb, wqkv, Qb, Kb, Vtb);

    attn_kernel<<<Bb * Hh * (Nn / 16), 64, 0, stream>>>(Qb, Kb, Vtb, AOb);

    gemm_proj<<<dim3(64, 12), 256, 0, stream>>>(AOb, wob, bo, (float*)d_out);
}